// Round 1
// baseline (38.620 us; speedup 1.0000x reference)
//
#include <hip/hip_runtime.h>

// GarNet aggregator: out[b,s,n] = wbar[b,s] * hi[b,s,n]
//   w    = exp(-d_av^2)                  [B,V,S]
//   hi   = (1/V) sum_v w[v,s]*fi[v,n]    [B,S,N]
//   wbar = (1/V) sum_v w[v,s]            [B,S]
// B=4096 V=128 S=16 N=64, fp32 in/out. Memory-bound (~185 MB @ ~6.3 TB/s).

#define B_ 4096
#define V_ 128
#define S_ 16
#define N_ 64

__global__ __launch_bounds__(256) void garnet_kernel(
    const float* __restrict__ fi,    // [B,V,N]
    const float* __restrict__ dav,   // [B,V,S]
    float* __restrict__ out)         // [B,S*N]
{
    // 8 KB + 32 KB = 40960 B exactly -> 4 blocks/CU
    __shared__ float w_lds[V_ * S_];     // [v][s]
    __shared__ float fi_lds[V_ * N_];    // [v][n]

    const int b   = blockIdx.x;
    const int tid = threadIdx.x;

    // ---- stage fi -> LDS (float4, 16B/lane coalesced) ----
    {
        const float4* src = (const float4*)(fi + (size_t)b * (V_ * N_));
        float4*       dst = (float4*)fi_lds;
#pragma unroll
        for (int i = 0; i < 8; ++i)           // 2048 float4 total
            dst[tid + i * 256] = src[tid + i * 256];
    }
    // ---- load d_av, compute w = exp(-d^2) -> LDS ----
    {
        const float4* src = (const float4*)(dav + (size_t)b * (V_ * S_));
        float4*       dst = (float4*)w_lds;
#pragma unroll
        for (int i = 0; i < 2; ++i) {         // 512 float4 total
            float4 v = src[tid + i * 256];
            float4 w;
            w.x = __expf(-v.x * v.x);
            w.y = __expf(-v.y * v.y);
            w.z = __expf(-v.z * v.z);
            w.w = __expf(-v.w * v.w);
            dst[tid + i * 256] = w;
        }
    }
    __syncthreads();

    const int wave = tid >> 6;     // 0..3 -> owns s in [4*wave, 4*wave+4)
    const int lane = tid & 63;     // n
    const int s0   = wave * 4;

    // ---- per-wave wbar reduction (each wave computes all 16, uses 4) ----
    // lane -> (sl = lane&15, vc = lane>>4); addresses 2-way bank aliased (free)
    float wb = 0.f;
    {
        const int sl = lane & 15;
        const int vc = lane >> 4;            // 0..3
#pragma unroll
        for (int j = 0; j < 32; ++j)
            wb += w_lds[(vc + 4 * j) * S_ + sl];
        wb += __shfl_xor(wb, 16, 64);        // reduce over vc bit 0
        wb += __shfl_xor(wb, 32, 64);        // reduce over vc bit 1
        // now lane l holds wbar_sum[l & 15]
    }
    const float wb0 = __shfl(wb, s0 + 0, 64);
    const float wb1 = __shfl(wb, s0 + 1, 64);
    const float wb2 = __shfl(wb, s0 + 2, 64);
    const float wb3 = __shfl(wb, s0 + 3, 64);

    // ---- main loop: hi[s0..s0+3][lane] ----
    float a0 = 0.f, a1 = 0.f, a2 = 0.f, a3 = 0.f;
#pragma unroll 8
    for (int v = 0; v < V_; ++v) {
        const float  f = fi_lds[v * N_ + lane];                 // 2-way, free
        const float4 w = *(const float4*)&w_lds[v * S_ + s0];   // broadcast
        a0 = fmaf(w.x, f, a0);
        a1 = fmaf(w.y, f, a1);
        a2 = fmaf(w.z, f, a2);
        a3 = fmaf(w.w, f, a3);
    }

    // ---- epilogue: out = wbar * hi / V^2 ----
    const float inv = 1.0f / ((float)V_ * (float)V_);
    float* ob = out + (size_t)b * (S_ * N_);
    ob[(s0 + 0) * N_ + lane] = wb0 * a0 * inv;
    ob[(s0 + 1) * N_ + lane] = wb1 * a1 * inv;
    ob[(s0 + 2) * N_ + lane] = wb2 * a2 * inv;
    ob[(s0 + 3) * N_ + lane] = wb3 * a3 * inv;
}

extern "C" void kernel_launch(void* const* d_in, const int* in_sizes, int n_in,
                              void* d_out, int out_size, void* d_ws, size_t ws_size,
                              hipStream_t stream) {
    const float* fi  = (const float*)d_in[0];   // fi_v  [B,V,N]
    const float* dav = (const float*)d_in[1];   // d_av  [B,V,S]
    float* o = (float*)d_out;                   // [B, S*N]
    garnet_kernel<<<B_, 256, 0, stream>>>(fi, dav, o);
}

// Round 2
// 37.568 us; speedup vs baseline: 1.0280x; 1.0280x over previous
//
#include <hip/hip_runtime.h>

// GarNet aggregator: out[b,s,n] = wbar[b,s] * hi[b,s,n] / V^2 (raw sums)
//   w    = exp(-d_av^2)            [B,V,S]
//   hi   = sum_v w[v,s]*fi[v,n]    [B,S,N]
//   wbar = sum_v w[v,s]            [B,S]
// B=4096 V=128 S=16 N=64, fp32. Memory-bound (~185 MB); fi streamed from
// global (read once, coalesced), w broadcast from LDS, cross-wave LDS reduce.

#define B_ 4096
#define V_ 128
#define S_ 16
#define N_ 64
#define VPW 32   // v's per wave

__global__ __launch_bounds__(256) void garnet_kernel(
    const float* __restrict__ fi,    // [B,V,N]
    const float* __restrict__ dav,   // [B,V,S]
    float* __restrict__ out)         // [B,S*N]
{
    __shared__ float w_lds[V_ * S_];        // 8 KB  [v][s]
    __shared__ float red[4 * N_ * S_];      // 16 KB [wave][n][s]

    const int b    = blockIdx.x;
    const int tid  = threadIdx.x;
    const int wave = tid >> 6;
    const int lane = tid & 63;              // = n in main loop & epilogue

    // ---- stage w = exp(-d^2) into LDS (float4 coalesced) ----
    {
        const float4* src = (const float4*)(dav + (size_t)b * (V_ * S_));
        float4*       dst = (float4*)w_lds;
#pragma unroll
        for (int i = 0; i < 2; ++i) {       // 512 float4 total
            float4 d = src[tid + i * 256];
            float4 w;
            w.x = __expf(-d.x * d.x);
            w.y = __expf(-d.y * d.y);
            w.z = __expf(-d.z * d.z);
            w.w = __expf(-d.w * d.w);
            dst[tid + i * 256] = w;
        }
    }
    __syncthreads();

    // ---- wbar sums: lane l ends with wbar_sum[l & 15] ----
    float wb = 0.f;
    {
        const int sl = lane & 15;
        const int vc = lane >> 4;           // 0..3, 2-way bank alias (free)
#pragma unroll
        for (int j = 0; j < 32; ++j)
            wb += w_lds[(vc + 4 * j) * S_ + sl];
        wb += __shfl_xor(wb, 16, 64);
        wb += __shfl_xor(wb, 32, 64);
    }
    const int   s0  = wave * 4;
    const float wb0 = __shfl(wb, s0 + 0, 64);
    const float wb1 = __shfl(wb, s0 + 1, 64);
    const float wb2 = __shfl(wb, s0 + 2, 64);
    const float wb3 = __shfl(wb, s0 + 3, 64);

    // ---- main loop: wave owns v in [32*wave, 32*wave+32), all 16 s ----
    float acc[S_];
#pragma unroll
    for (int s = 0; s < S_; ++s) acc[s] = 0.f;

    const float* fib  = fi + (size_t)b * (V_ * N_) + (size_t)(wave * VPW) * N_ + lane;
    const float* wrow = &w_lds[(wave * VPW) * S_];
#pragma unroll 8
    for (int v = 0; v < VPW; ++v) {
        const float  f  = fib[(size_t)v * N_];                 // coalesced global
        const float4 w0 = *(const float4*)&wrow[v * S_ + 0];   // LDS broadcast
        const float4 w1 = *(const float4*)&wrow[v * S_ + 4];
        const float4 w2 = *(const float4*)&wrow[v * S_ + 8];
        const float4 w3 = *(const float4*)&wrow[v * S_ + 12];
        acc[0]  = fmaf(w0.x, f, acc[0]);
        acc[1]  = fmaf(w0.y, f, acc[1]);
        acc[2]  = fmaf(w0.z, f, acc[2]);
        acc[3]  = fmaf(w0.w, f, acc[3]);
        acc[4]  = fmaf(w1.x, f, acc[4]);
        acc[5]  = fmaf(w1.y, f, acc[5]);
        acc[6]  = fmaf(w1.z, f, acc[6]);
        acc[7]  = fmaf(w1.w, f, acc[7]);
        acc[8]  = fmaf(w2.x, f, acc[8]);
        acc[9]  = fmaf(w2.y, f, acc[9]);
        acc[10] = fmaf(w2.z, f, acc[10]);
        acc[11] = fmaf(w2.w, f, acc[11]);
        acc[12] = fmaf(w3.x, f, acc[12]);
        acc[13] = fmaf(w3.y, f, acc[13]);
        acc[14] = fmaf(w3.z, f, acc[14]);
        acc[15] = fmaf(w3.w, f, acc[15]);
    }

    // ---- cross-wave reduce via LDS: red[wave][n][s] (2-way alias, free) ----
    {
        float4* dst = (float4*)&red[(wave * N_ + lane) * S_];
        dst[0] = make_float4(acc[0],  acc[1],  acc[2],  acc[3]);
        dst[1] = make_float4(acc[4],  acc[5],  acc[6],  acc[7]);
        dst[2] = make_float4(acc[8],  acc[9],  acc[10], acc[11]);
        dst[3] = make_float4(acc[12], acc[13], acc[14], acc[15]);
    }
    __syncthreads();

    float4 h = make_float4(0.f, 0.f, 0.f, 0.f);
#pragma unroll
    for (int w = 0; w < 4; ++w) {
        const float4 r = *(const float4*)&red[(w * N_ + lane) * S_ + s0];
        h.x += r.x; h.y += r.y; h.z += r.z; h.w += r.w;
    }

    // ---- epilogue: out[s0+j][lane] = wbar[s0+j] * hi[s0+j][lane] / V^2 ----
    const float inv = 1.0f / ((float)V_ * (float)V_);
    float* ob = out + (size_t)b * (S_ * N_);
    ob[(s0 + 0) * N_ + lane] = wb0 * h.x * inv;
    ob[(s0 + 1) * N_ + lane] = wb1 * h.y * inv;
    ob[(s0 + 2) * N_ + lane] = wb2 * h.z * inv;
    ob[(s0 + 3) * N_ + lane] = wb3 * h.w * inv;
}

extern "C" void kernel_launch(void* const* d_in, const int* in_sizes, int n_in,
                              void* d_out, int out_size, void* d_ws, size_t ws_size,
                              hipStream_t stream) {
    const float* fi  = (const float*)d_in[0];   // fi_v  [B,V,N]
    const float* dav = (const float*)d_in[1];   // d_av  [B,V,S]
    float* o = (float*)d_out;                   // [B, S*N]
    garnet_kernel<<<B_, 256, 0, stream>>>(fi, dav, o);
}

// Round 3
// 31.822 us; speedup vs baseline: 1.2136x; 1.1806x over previous
//
#include <hip/hip_runtime.h>
#include <hip/hip_bf16.h>

// GarNet aggregator via bf16 MFMA, zero LDS.
//   w    = exp(-d_av^2)             [B,V,S]
//   hi   = sum_v w[v,s]*fi[v,n]     -> MFMA: A = w^T (16x128), B = fi (128x64)
//   out  = (sum_v w[v,s]) * hi / V^2
// B=4096 V=128 S=16 N=64, fp32 in/out. One wave per batch, 16 MFMAs/batch.
// Fragments assembled directly from global (64B-segment coalesced loads);
// no LDS at all -> the w-broadcast LDS-return-path cost (~23 us/CU in R1/R2)
// is eliminated. bf16 inputs, fp32 accum; wbar kept fp32.
//
// mfma_f32_16x16x32_bf16 layouts (learn_hip m89/m91 verified):
//   A frag: lane = 16*(k>>3) + row,  elem j -> k = (lane>>4)*8 + j, row = lane&15
//   B frag: lane = 16*(k>>3) + col,  same k mapping
//   C/D:    col = lane&15, row = (lane>>4)*4 + reg

#define B_ 4096
#define V_ 128
#define S_ 16
#define N_ 64

typedef __attribute__((ext_vector_type(8))) short bf16x8;
typedef __attribute__((ext_vector_type(4))) float f32x4;

__device__ __forceinline__ short to_bf16(float x) {
    return (short)__bfloat16_as_ushort(__float2bfloat16(x));  // RNE
}

__global__ __launch_bounds__(256) void garnet_kernel(
    const float* __restrict__ fi,    // [B,V,N]
    const float* __restrict__ dav,   // [B,V,S]
    float* __restrict__ out)         // [B,S*N]
{
    const int tid  = threadIdx.x;
    const int wave = tid >> 6;
    const int lane = tid & 63;
    const int b    = blockIdx.x * 4 + wave;   // one wave per batch

    const int g   = lane >> 4;   // k-group 0..3
    const int col = lane & 15;   // s (A-side / wbar), n-col (B-side)

    const float* davb = dav + (size_t)b * (V_ * S_);
    const float* fib  = fi  + (size_t)b * (V_ * N_);

    f32x4 acc[4];
#pragma unroll
    for (int nt = 0; nt < 4; ++nt) acc[nt] = (f32x4){0.f, 0.f, 0.f, 0.f};

    float wbp = 0.f;   // partial wbar_sum for s = col

#pragma unroll
    for (int t = 0; t < 4; ++t) {           // k-step: v in [32t, 32t+32)
        const int v0 = t * 32 + g * 8;

        // ---- A fragment: w^T[s=col][k] = exp(-dav[v0+j][col]^2) ----
        float wv[8];
#pragma unroll
        for (int j = 0; j < 8; ++j) {
            const float d = davb[(v0 + j) * S_ + col];   // 4x64B segments/instr
            wv[j] = __expf(-d * d);
        }
        bf16x8 afrag;
#pragma unroll
        for (int j = 0; j < 8; ++j) {
            wbp += wv[j];
            afrag[j] = to_bf16(wv[j]);
        }

        // ---- B fragments (per n-tile) + MFMA ----
#pragma unroll
        for (int nt = 0; nt < 4; ++nt) {
            bf16x8 bfrag;
#pragma unroll
            for (int j = 0; j < 8; ++j) {
                const float f = fib[(v0 + j) * N_ + nt * 16 + col];
                bfrag[j] = to_bf16(f);
            }
            acc[nt] = __builtin_amdgcn_mfma_f32_16x16x32_bf16(afrag, bfrag, acc[nt], 0, 0, 0);
        }
    }

    // ---- wbar: reduce partials across the 4 k-groups (lanes same col) ----
    wbp += __shfl_xor(wbp, 16, 64);
    wbp += __shfl_xor(wbp, 32, 64);
    // every lane now holds wbar_sum[lane & 15]

    // ---- epilogue: out[s][n] = wbar_sum[s] * hi_sum[s][n] / V^2 ----
    const float inv = 1.0f / ((float)V_ * (float)V_);
    float* ob = out + (size_t)b * (S_ * N_);
#pragma unroll
    for (int r = 0; r < 4; ++r) {
        const int   s   = g * 4 + r;                 // D row
        const float wbs = __shfl(wbp, s, 64);        // wbar_sum[s]
#pragma unroll
        for (int nt = 0; nt < 4; ++nt)
            ob[s * N_ + nt * 16 + col] = wbs * acc[nt][r] * inv;
    }
}

extern "C" void kernel_launch(void* const* d_in, const int* in_sizes, int n_in,
                              void* d_out, int out_size, void* d_ws, size_t ws_size,
                              hipStream_t stream) {
    const float* fi  = (const float*)d_in[0];   // fi_v  [B,V,N]
    const float* dav = (const float*)d_in[1];   // d_av  [B,V,S]
    float* o = (float*)d_out;                   // [B, S*N]
    garnet_kernel<<<B_ / 4, 256, 0, stream>>>(fi, dav, o);
}